// Round 1
// baseline (2346.183 us; speedup 1.0000x reference)
//
#include <hip/hip_runtime.h>
#include <hip/hip_bf16.h>

#define N_NODES 50000
#define E_EDGES 300000
#define IN_F 512
#define H_F 256
#define OUT_F 256
#define K_CL 4096

__device__ __forceinline__ unsigned fkey(float f) {
    unsigned u = __float_as_uint(f);
    return (u & 0x80000000u) ? ~u : (u | 0x80000000u);
}

// ---------------- init ----------------
__global__ __launch_bounds__(256) void init_nodes(float* degD, int* degS,
                                                  unsigned long long* best_enc,
                                                  unsigned long long* bestpack, int* bgnode) {
    int i = blockIdx.x * blockDim.x + threadIdx.x;
    if (i < N_NODES) { degD[i] = 1.0f; degS[i] = 0; best_enc[i] = 0ULL; }
    if (i == 0) { *bestpack = 0ULL; *bgnode = 0x7FFFFFFF; }
}

__global__ __launch_bounds__(256) void deg_edges(const int* __restrict__ src,
                                                 const int* __restrict__ dst,
                                                 float* degD, int* degS) {
    int e = blockIdx.x * blockDim.x + threadIdx.x;
    if (e >= E_EDGES) return;
    atomicAdd(&degD[dst[e]], 1.0f);
    atomicAdd(&degS[src[e]], 1);
}

__global__ __launch_bounds__(256) void make_dinv(float* degD) {
    int i = blockIdx.x * blockDim.x + threadIdx.x;
    if (i < N_NODES) degD[i] = rsqrtf(degD[i]);
}

// ---------------- generic fp32 tiled GEMM: C = A(MxKd) @ B(KdxNc) ----------------
#define BM 64
#define BN 64
#define BKT 16
__global__ __launch_bounds__(256) void gemm_f32(const float* __restrict__ A,
                                                const float* __restrict__ B,
                                                float* __restrict__ C,
                                                int M, int Nc, int Kd) {
    __shared__ float As[BKT][BM + 1];
    __shared__ float Bs[BKT][BN + 1];
    int tid = threadIdx.x;
    int tx = tid % 16, ty = tid / 16;
    int row0 = blockIdx.y * BM;
    int col0 = blockIdx.x * BN;
    float acc[4][4] = {};
    for (int k0 = 0; k0 < Kd; k0 += BKT) {
        for (int t = tid; t < BM * BKT; t += 256) {
            int m = t / BKT, k = t % BKT;
            int gr = row0 + m, gk = k0 + k;
            float v = 0.f;
            if (gr < M && gk < Kd) v = A[(long)gr * Kd + gk];
            As[k][m] = v;
        }
        for (int t = tid; t < BKT * BN; t += 256) {
            int k = t / BN, n = t % BN;
            int gk = k0 + k, gc = col0 + n;
            float v = 0.f;
            if (gk < Kd && gc < Nc) v = B[(long)gk * Nc + gc];
            Bs[k][n] = v;
        }
        __syncthreads();
        #pragma unroll
        for (int k = 0; k < BKT; ++k) {
            float a[4], b[4];
            #pragma unroll
            for (int i = 0; i < 4; ++i) a[i] = As[k][ty * 4 + i];
            #pragma unroll
            for (int j = 0; j < 4; ++j) b[j] = Bs[k][tx * 4 + j];
            #pragma unroll
            for (int i = 0; i < 4; ++i)
                #pragma unroll
                for (int j = 0; j < 4; ++j) acc[i][j] += a[i] * b[j];
        }
        __syncthreads();
    }
    for (int i = 0; i < 4; ++i) {
        int gr = row0 + ty * 4 + i;
        if (gr >= M) continue;
        for (int j = 0; j < 4; ++j) {
            int gc = col0 + tx * 4 + j;
            if (gc < Nc) C[(long)gr * Nc + gc] = acc[i][j];
        }
    }
}

// ---------------- conv1 aggregation ----------------
__global__ __launch_bounds__(256) void self_init(const float* __restrict__ h,
                                                 const float* __restrict__ dinv, float* x1) {
    int i = blockIdx.x, j = threadIdx.x;
    float c = dinv[i] * dinv[i];
    x1[(long)i * H_F + j] = c * h[(long)i * H_F + j];
}

__global__ __launch_bounds__(256) void edge_agg(const int* __restrict__ src,
                                                const int* __restrict__ dst,
                                                const float* __restrict__ h,
                                                const float* __restrict__ dinv, float* x1) {
    int e = blockIdx.x, j = threadIdx.x;
    int s = src[e], d = dst[e];
    float coef = dinv[s] * dinv[d];
    atomicAdd(&x1[(long)d * H_F + j], coef * h[(long)s * H_F + j]);
}

__global__ __launch_bounds__(256) void relu_score(float* x1, const float* __restrict__ b1,
                                                  const float* __restrict__ w_score, float* raw) {
    __shared__ float red[256];
    int i = blockIdx.x, j = threadIdx.x;
    float v = x1[(long)i * H_F + j] + b1[j];
    v = fmaxf(v, 0.f);
    x1[(long)i * H_F + j] = v;
    red[j] = v * w_score[j];
    __syncthreads();
    for (int off = 128; off > 0; off >>= 1) {
        if (j < off) red[j] += red[j + off];
        __syncthreads();
    }
    if (j == 0) raw[i] = red[0];
}

// ---------------- top-K select (single block radix) ----------------
__global__ __launch_bounds__(1024) void topk_select(const float* __restrict__ raw,
                                                    unsigned* outT, int* outNeedEq) {
    __shared__ unsigned hist[256];
    __shared__ unsigned sh_prefix;
    __shared__ int sh_k;
    int tid = threadIdx.x;
    if (tid == 0) { sh_prefix = 0; sh_k = K_CL; }
    __syncthreads();
    for (int byte = 3; byte >= 0; --byte) {
        if (tid < 256) hist[tid] = 0;
        __syncthreads();
        unsigned prefix = sh_prefix;
        unsigned known_mask = (byte == 3) ? 0u : (0xFFFFFFFFu << ((byte + 1) * 8));
        for (int i = tid; i < N_NODES; i += 1024) {
            unsigned key = fkey(raw[i]);
            if ((key & known_mask) == prefix)
                atomicAdd(&hist[(key >> (byte * 8)) & 255], 1u);
        }
        __syncthreads();
        if (tid == 0) {
            int kk = sh_k;
            int cum = 0;
            int v = 255;
            for (; v > 0; --v) {
                int c = (int)hist[v];
                if (cum + c >= kk) break;
                cum += c;
            }
            sh_prefix = prefix | ((unsigned)v << (byte * 8));
            sh_k = kk - cum;
        }
        __syncthreads();
    }
    if (tid == 0) { *outT = sh_prefix; *outNeedEq = sh_k; }
}

// ---------------- deterministic ordered compaction ----------------
__global__ __launch_bounds__(1024) void topk_compact(const float* __restrict__ raw,
                                                     const unsigned* pT, const int* pNeedEq,
                                                     int* keep, int* cid) {
    __shared__ int s_gt[1024], s_eq[1024];
    int tid = threadIdx.x;
    unsigned T = *pT;
    int needEq = *pNeedEq;
    int chunk = (N_NODES + 1023) / 1024;
    int lo = tid * chunk;
    int hi = lo + chunk; if (hi > N_NODES) hi = N_NODES;
    int cgt = 0, ceq = 0;
    for (int i = lo; i < hi; ++i) {
        unsigned k = fkey(raw[i]);
        if (k > T) cgt++;
        else if (k == T) ceq++;
    }
    s_gt[tid] = cgt; s_eq[tid] = ceq;
    __syncthreads();
    for (int off = 1; off < 1024; off <<= 1) {
        int a = (tid >= off) ? s_gt[tid - off] : 0;
        int b = (tid >= off) ? s_eq[tid - off] : 0;
        __syncthreads();
        s_gt[tid] += a; s_eq[tid] += b;
        __syncthreads();
    }
    int totalGt = s_gt[1023];
    int g = s_gt[tid] - cgt;   // exclusive prefix
    int e = s_eq[tid] - ceq;
    for (int i = lo; i < hi; ++i) {
        unsigned k = fkey(raw[i]);
        if (k > T) { keep[i] = 1; cid[i] = g; g++; }
        else if (k == T) {
            if (e < needEq) { keep[i] = 1; cid[i] = totalGt + e; }
            else { keep[i] = 0; cid[i] = -1; }
            e++;
        } else { keep[i] = 0; cid[i] = -1; }
    }
}

// ---------------- global fallback cluster ----------------
__global__ __launch_bounds__(256) void bg_pack(const int* __restrict__ keep,
                                               const int* __restrict__ degS,
                                               const float* __restrict__ raw,
                                               unsigned long long* bestpack) {
    int i = blockIdx.x * blockDim.x + threadIdx.x;
    if (i < N_NODES && keep[i]) {
        unsigned long long p = ((unsigned long long)(unsigned)degS[i] << 32) | fkey(raw[i]);
        atomicMax(bestpack, p);
    }
}

__global__ __launch_bounds__(256) void bg_node(const int* __restrict__ keep,
                                               const int* __restrict__ degS,
                                               const float* __restrict__ raw,
                                               const unsigned long long* bestpack, int* bgnode) {
    int i = blockIdx.x * blockDim.x + threadIdx.x;
    if (i < N_NODES && keep[i]) {
        unsigned long long p = ((unsigned long long)(unsigned)degS[i] << 32) | fkey(raw[i]);
        if (p == *bestpack) atomicMin(bgnode, i);
    }
}

// ---------------- neighbor attachment ----------------
__global__ __launch_bounds__(256) void neigh_edges(const int* __restrict__ src,
                                                   const int* __restrict__ dst,
                                                   const int* __restrict__ keep,
                                                   const int* __restrict__ degS,
                                                   unsigned long long* best_enc) {
    int e = blockIdx.x * blockDim.x + threadIdx.x;
    if (e >= 2 * E_EDGES) return;
    int s, t;
    if (e < E_EDGES) { s = src[e]; t = dst[e]; }
    else { s = dst[e - E_EDGES]; t = src[e - E_EDGES]; }
    if (!keep[s] && keep[t]) {
        unsigned long long enc =
            (unsigned long long)((long long)degS[t] * N_NODES + (N_NODES - 1 - t)) + 1ULL;
        atomicMax(&best_enc[s], enc);
    }
}

__global__ __launch_bounds__(256) void resolve_cid(const int* __restrict__ keep,
                                                   const unsigned long long* __restrict__ best_enc,
                                                   const int* __restrict__ bgnode, int* cid) {
    int i = blockIdx.x * blockDim.x + threadIdx.x;
    if (i >= N_NODES) return;
    if (keep[i]) return;
    unsigned long long v = best_enc[i];
    if (v > 0ULL) {
        long long enc = (long long)(v - 1ULL);
        int t = (N_NODES - 1) - (int)(enc % N_NODES);
        cid[i] = cid[t];
    } else {
        cid[i] = cid[*bgnode];
    }
}

// ---------------- pooling ----------------
__global__ __launch_bounds__(256) void pool_add(const float* __restrict__ x1,
                                                const float* __restrict__ raw,
                                                const int* __restrict__ cid,
                                                float* xp, float* cnt) {
    int i = blockIdx.x, j = threadIdx.x;
    int c = cid[i];
    float g = tanhf(raw[i]);
    atomicAdd(&xp[(long)c * H_F + j], x1[(long)i * H_F + j] * g);
    if (j == 0) atomicAdd(&cnt[c], 1.0f);
}

__global__ __launch_bounds__(256) void pool_div(float* xp, const float* __restrict__ cnt) {
    int i = blockIdx.x, j = threadIdx.x;
    float c = fmaxf(cnt[i], 1.0f);
    xp[(long)i * H_F + j] /= c;
}

// ---------------- pooled adjacency ----------------
__global__ __launch_bounds__(256) void build_A(const int* __restrict__ src,
                                               const int* __restrict__ dst,
                                               const int* __restrict__ cid, float* Adense) {
    int e = blockIdx.x * blockDim.x + threadIdx.x;
    if (e >= E_EDGES) return;
    int cu = cid[src[e]], cv = cid[dst[e]];
    if (cu != cv) Adense[(long)cv * K_CL + cu] = 1.0f;
}

__global__ __launch_bounds__(256) void rowsum_di(const float* __restrict__ Adense, float* di) {
    __shared__ float red[256];
    int i = blockIdx.x, t = threadIdx.x;
    float s = 0.f;
    for (int j = t; j < K_CL; j += 256) s += Adense[(long)i * K_CL + j];
    red[t] = s;
    __syncthreads();
    for (int off = 128; off > 0; off >>= 1) {
        if (t < off) red[t] += red[t + off];
        __syncthreads();
    }
    if (t == 0) di[i] = rsqrtf(red[0] + 1.0f);
}

__global__ __launch_bounds__(256) void scale_rows(const float* __restrict__ xpW2,
                                                  const float* __restrict__ di, float* Yp) {
    int i = blockIdx.x, j = threadIdx.x;
    Yp[(long)i * H_F + j] = di[i] * xpW2[(long)i * H_F + j];
}

__global__ __launch_bounds__(256) void epilogue_xp2(const float* __restrict__ Z,
                                                    const float* __restrict__ Yp,
                                                    const float* __restrict__ di,
                                                    const float* __restrict__ b2, float* xp2) {
    int i = blockIdx.x, j = threadIdx.x;
    xp2[(long)i * H_F + j] = di[i] * (Z[(long)i * H_F + j] + Yp[(long)i * H_F + j]) + b2[j];
}

// ---------------- final add ----------------
__global__ __launch_bounds__(256) void final_add(float* out, const float* __restrict__ xp2,
                                                 const int* __restrict__ cid,
                                                 const float* __restrict__ b_skip) {
    int i = blockIdx.x, j = threadIdx.x;
    int c = cid[i];
    out[(long)i * OUT_F + j] += xp2[(long)c * OUT_F + j] + b_skip[j];
}

// ---------------- host launch ----------------
static inline size_t align256(size_t x) { return (x + 255) & ~(size_t)255; }

extern "C" void kernel_launch(void* const* d_in, const int* in_sizes, int n_in,
                              void* d_out, int out_size, void* d_ws, size_t ws_size,
                              hipStream_t stream) {
    const float* x      = (const float*)d_in[0];
    const int*   eidx   = (const int*)d_in[1];
    const float* W1     = (const float*)d_in[2];
    const float* b1     = (const float*)d_in[3];
    const float* W2     = (const float*)d_in[4];
    const float* b2     = (const float*)d_in[5];
    const float* wscore = (const float*)d_in[6];
    const float* Wskip  = (const float*)d_in[7];
    const float* bskip  = (const float*)d_in[8];
    float* out = (float*)d_out;

    const int* src = eidx;
    const int* dst = eidx + E_EDGES;

    char* ws = (char*)d_ws;
    size_t off = 0;
    auto alloc = [&](size_t bytes) { char* p = ws + off; off += align256(bytes); return p; };

    float* h     = (float*)alloc((size_t)N_NODES * H_F * 4);
    float* x1    = (float*)alloc((size_t)N_NODES * H_F * 4);
    float* raw   = (float*)alloc((size_t)N_NODES * 4);
    float* dinv  = (float*)alloc((size_t)N_NODES * 4);   // degD then dinv in-place
    int*   degS  = (int*)alloc((size_t)N_NODES * 4);
    int*   keep  = (int*)alloc((size_t)N_NODES * 4);
    int*   cid   = (int*)alloc((size_t)N_NODES * 4);
    unsigned long long* best_enc = (unsigned long long*)alloc((size_t)N_NODES * 8);
    char*  small = alloc(64);
    unsigned* selT = (unsigned*)(small + 0);
    int* needEq    = (int*)(small + 4);
    unsigned long long* bestpack = (unsigned long long*)(small + 8);
    int* bgnode    = (int*)(small + 16);
    float* xp    = (float*)alloc((size_t)K_CL * H_F * 4);
    float* cnt   = (float*)alloc((size_t)K_CL * 4);
    float* Adense= (float*)alloc((size_t)K_CL * K_CL * 4);
    float* di    = (float*)alloc((size_t)K_CL * 4);
    float* xpW2  = (float*)alloc((size_t)K_CL * H_F * 4);
    float* Yp    = (float*)alloc((size_t)K_CL * H_F * 4);
    float* Zbuf  = (float*)alloc((size_t)K_CL * H_F * 4);
    float* xp2   = (float*)alloc((size_t)K_CL * H_F * 4);
    (void)ws_size; (void)n_in; (void)in_sizes; (void)out_size;

    int nb = (N_NODES + 255) / 256;
    int eb = (E_EDGES + 255) / 256;

    // degrees
    init_nodes<<<nb, 256, 0, stream>>>(dinv, degS, best_enc, bestpack, bgnode);
    deg_edges<<<eb, 256, 0, stream>>>(src, dst, dinv, degS);
    make_dinv<<<nb, 256, 0, stream>>>(dinv);

    // h = x @ W1
    {
        dim3 grid((H_F + BN - 1) / BN, (N_NODES + BM - 1) / BM);
        gemm_f32<<<grid, 256, 0, stream>>>(x, W1, h, N_NODES, H_F, IN_F);
    }

    // conv1 aggregation
    self_init<<<N_NODES, 256, 0, stream>>>(h, dinv, x1);
    edge_agg<<<E_EDGES, 256, 0, stream>>>(src, dst, h, dinv, x1);
    relu_score<<<N_NODES, 256, 0, stream>>>(x1, b1, wscore, raw);

    // top-K
    topk_select<<<1, 1024, 0, stream>>>(raw, selT, needEq);
    topk_compact<<<1, 1024, 0, stream>>>(raw, selT, needEq, keep, cid);

    // fallback cluster
    bg_pack<<<nb, 256, 0, stream>>>(keep, degS, raw, bestpack);
    bg_node<<<nb, 256, 0, stream>>>(keep, degS, raw, bestpack, bgnode);

    // neighbor attachment
    neigh_edges<<<(2 * E_EDGES + 255) / 256, 256, 0, stream>>>(src, dst, keep, degS, best_enc);
    resolve_cid<<<nb, 256, 0, stream>>>(keep, best_enc, bgnode, cid);

    // pooling
    hipMemsetAsync(xp, 0, (size_t)K_CL * H_F * 4, stream);
    hipMemsetAsync(cnt, 0, (size_t)K_CL * 4, stream);
    pool_add<<<N_NODES, 256, 0, stream>>>(x1, raw, cid, xp, cnt);
    pool_div<<<K_CL, 256, 0, stream>>>(xp, cnt);

    // pooled adjacency
    hipMemsetAsync(Adense, 0, (size_t)K_CL * K_CL * 4, stream);
    build_A<<<eb, 256, 0, stream>>>(src, dst, cid, Adense);
    rowsum_di<<<K_CL, 256, 0, stream>>>(Adense, di);

    // conv2 on pooled graph
    {
        dim3 grid((H_F + BN - 1) / BN, (K_CL + BM - 1) / BM);
        gemm_f32<<<grid, 256, 0, stream>>>(xp, W2, xpW2, K_CL, H_F, H_F);
    }
    scale_rows<<<K_CL, 256, 0, stream>>>(xpW2, di, Yp);
    {
        dim3 grid((H_F + BN - 1) / BN, (K_CL + BM - 1) / BM);
        gemm_f32<<<grid, 256, 0, stream>>>(Adense, Yp, Zbuf, K_CL, H_F, K_CL);
    }
    epilogue_xp2<<<K_CL, 256, 0, stream>>>(Zbuf, Yp, di, b2, xp2);

    // skip connection GEMM straight into out
    {
        dim3 grid((OUT_F + BN - 1) / BN, (N_NODES + BM - 1) / BM);
        gemm_f32<<<grid, 256, 0, stream>>>(x1, Wskip, out, N_NODES, OUT_F, H_F);
    }
    final_add<<<N_NODES, 256, 0, stream>>>(out, xp2, cid, bskip);
}

// Round 2
// 1602.915 us; speedup vs baseline: 1.4637x; 1.4637x over previous
//
#include <hip/hip_runtime.h>
#include <hip/hip_bf16.h>

#define N_NODES 50000
#define E_EDGES 300000
#define IN_F 512
#define H_F 256
#define OUT_F 256
#define K_CL 4096
#define KW (K_CL / 32)

__device__ __forceinline__ unsigned fkey(float f) {
    unsigned u = __float_as_uint(f);
    return (u & 0x80000000u) ? ~u : (u | 0x80000000u);
}

// ---------------- init ----------------
__global__ __launch_bounds__(256) void init_nodes(int* cntD, int* degS,
                                                  unsigned long long* best_enc,
                                                  unsigned long long* bestpack, int* bgnode) {
    int i = blockIdx.x * blockDim.x + threadIdx.x;
    if (i < N_NODES) { cntD[i] = 0; degS[i] = 0; best_enc[i] = 0ULL; }
    if (i == 0) { *bestpack = 0ULL; *bgnode = 0x7FFFFFFF; }
}

__global__ __launch_bounds__(256) void deg_edges(const int* __restrict__ src,
                                                 const int* __restrict__ dst,
                                                 int* cntD, int* degS) {
    int e = blockIdx.x * blockDim.x + threadIdx.x;
    if (e >= E_EDGES) return;
    atomicAdd(&cntD[dst[e]], 1);
    atomicAdd(&degS[src[e]], 1);
}

__global__ __launch_bounds__(256) void make_dinv(const int* __restrict__ cntD, float* dinv) {
    int i = blockIdx.x * blockDim.x + threadIdx.x;
    if (i < N_NODES) dinv[i] = rsqrtf((float)cntD[i] + 1.0f);
}

// ---------------- fast fp32 GEMM: C = A(MxKd) @ B(KdxNc); Nc%128==0, Kd%16==0 ----------------
#define GBM 128
#define GBN 128
#define GBK 16
__global__ __launch_bounds__(256) void gemm_fast(const float* __restrict__ A,
                                                 const float* __restrict__ B,
                                                 float* __restrict__ C,
                                                 int M, int Nc, int Kd) {
    __shared__ float As[GBK][GBM];
    __shared__ float Bs[GBK][GBN];
    int tid = threadIdx.x;
    int tx = tid & 15, ty = tid >> 4;
    int row0 = blockIdx.y * GBM, col0 = blockIdx.x * GBN;
    float acc[2][2][4][4] = {};

    for (int k0 = 0; k0 < Kd; k0 += GBK) {
        // load A tile (transposed store), 512 float4s
        #pragma unroll
        for (int half = 0; half < 2; ++half) {
            int f = tid + half * 256;
            int r = f >> 2, kq = f & 3;
            int gr = row0 + r;
            float4 v = {0.f, 0.f, 0.f, 0.f};
            if (gr < M) v = *(const float4*)&A[(long)gr * Kd + k0 + kq * 4];
            As[kq * 4 + 0][r] = v.x;
            As[kq * 4 + 1][r] = v.y;
            As[kq * 4 + 2][r] = v.z;
            As[kq * 4 + 3][r] = v.w;
        }
        // load B tile, 512 float4s
        #pragma unroll
        for (int half = 0; half < 2; ++half) {
            int f = tid + half * 256;
            int k = f >> 5, c4 = f & 31;
            float4 v = *(const float4*)&B[(long)(k0 + k) * Nc + col0 + c4 * 4];
            *(float4*)&Bs[k][c4 * 4] = v;
        }
        __syncthreads();
        #pragma unroll
        for (int k = 0; k < GBK; ++k) {
            float4 a0 = *(const float4*)&As[k][ty * 4];
            float4 a1 = *(const float4*)&As[k][ty * 4 + 64];
            float4 b0 = *(const float4*)&Bs[k][tx * 4];
            float4 b1 = *(const float4*)&Bs[k][tx * 4 + 64];
            float av[2][4] = {{a0.x, a0.y, a0.z, a0.w}, {a1.x, a1.y, a1.z, a1.w}};
            float bv[2][4] = {{b0.x, b0.y, b0.z, b0.w}, {b1.x, b1.y, b1.z, b1.w}};
            #pragma unroll
            for (int ri = 0; ri < 2; ++ri)
                #pragma unroll
                for (int ci = 0; ci < 2; ++ci)
                    #pragma unroll
                    for (int i = 0; i < 4; ++i)
                        #pragma unroll
                        for (int j = 0; j < 4; ++j)
                            acc[ri][ci][i][j] += av[ri][i] * bv[ci][j];
        }
        __syncthreads();
    }
    #pragma unroll
    for (int ri = 0; ri < 2; ++ri)
        #pragma unroll
        for (int i = 0; i < 4; ++i) {
            int gr = row0 + ri * 64 + ty * 4 + i;
            if (gr >= M) continue;
            #pragma unroll
            for (int ci = 0; ci < 2; ++ci) {
                float4 o = {acc[ri][ci][i][0], acc[ri][ci][i][1],
                            acc[ri][ci][i][2], acc[ri][ci][i][3]};
                *(float4*)&C[(long)gr * Nc + col0 + ci * 64 + tx * 4] = o;
            }
        }
}

// ---------------- CSR build ----------------
__global__ __launch_bounds__(1024) void scan_rowptr(const int* __restrict__ cnt,
                                                    int* rowptr, int* cur) {
    __shared__ int s[1024];
    int tid = threadIdx.x;
    const int CH = (N_NODES + 1023) / 1024;
    int lo = tid * CH;
    int hi = lo + CH; if (hi > N_NODES) hi = N_NODES;
    int sum = 0;
    for (int i = lo; i < hi; ++i) sum += cnt[i];
    s[tid] = sum;
    __syncthreads();
    for (int off = 1; off < 1024; off <<= 1) {
        int v = (tid >= off) ? s[tid - off] : 0;
        __syncthreads();
        s[tid] += v;
        __syncthreads();
    }
    int run = s[tid] - sum;  // exclusive prefix
    for (int i = lo; i < hi; ++i) {
        rowptr[i] = run; cur[i] = run; run += cnt[i];
    }
    if (tid == 1023) rowptr[N_NODES] = s[1023];
}

__global__ __launch_bounds__(256) void csr_scatter(const int* __restrict__ src,
                                                   const int* __restrict__ dst,
                                                   int* cur, int* csr) {
    int e = blockIdx.x * blockDim.x + threadIdx.x;
    if (e >= E_EDGES) return;
    int d = dst[e];
    int p = atomicAdd(&cur[d], 1);
    csr[p] = src[e];
}

// ---------------- fused conv1 aggregation + relu + score ----------------
__global__ __launch_bounds__(256) void agg_fused(const float* __restrict__ h,
                                                 const float* __restrict__ dinv,
                                                 const int* __restrict__ rowptr,
                                                 const int* __restrict__ csr,
                                                 const float* __restrict__ b1,
                                                 const float* __restrict__ w_score,
                                                 float* x1, float* raw) {
    __shared__ int s_src[128];
    __shared__ float s_cf[128];
    __shared__ float red[256];
    int i = blockIdx.x, j = threadIdx.x;
    float di_ = dinv[i];
    float acc = di_ * di_ * h[(long)i * H_F + j];
    int p0 = rowptr[i], p1 = rowptr[i + 1];
    for (int base = p0; base < p1; base += 128) {
        int m = p1 - base; if (m > 128) m = 128;
        if (j < m) { int s = csr[base + j]; s_src[j] = s; s_cf[j] = dinv[s]; }
        __syncthreads();
        for (int t = 0; t < m; ++t)
            acc += (s_cf[t] * di_) * h[(long)s_src[t] * H_F + j];
        __syncthreads();
    }
    float v = fmaxf(acc + b1[j], 0.f);
    x1[(long)i * H_F + j] = v;
    red[j] = v * w_score[j];
    __syncthreads();
    for (int off = 128; off > 0; off >>= 1) {
        if (j < off) red[j] += red[j + off];
        __syncthreads();
    }
    if (j == 0) raw[i] = red[0];
}

// ---------------- top-K select (single block radix) ----------------
__global__ __launch_bounds__(1024) void topk_select(const float* __restrict__ raw,
                                                    unsigned* outT, int* outNeedEq) {
    __shared__ unsigned hist[256];
    __shared__ unsigned sh_prefix;
    __shared__ int sh_k;
    int tid = threadIdx.x;
    if (tid == 0) { sh_prefix = 0; sh_k = K_CL; }
    __syncthreads();
    for (int byte = 3; byte >= 0; --byte) {
        if (tid < 256) hist[tid] = 0;
        __syncthreads();
        unsigned prefix = sh_prefix;
        unsigned known_mask = (byte == 3) ? 0u : (0xFFFFFFFFu << ((byte + 1) * 8));
        for (int i = tid; i < N_NODES; i += 1024) {
            unsigned key = fkey(raw[i]);
            if ((key & known_mask) == prefix)
                atomicAdd(&hist[(key >> (byte * 8)) & 255], 1u);
        }
        __syncthreads();
        if (tid == 0) {
            int kk = sh_k;
            int cum = 0;
            int v = 255;
            for (; v > 0; --v) {
                int c = (int)hist[v];
                if (cum + c >= kk) break;
                cum += c;
            }
            sh_prefix = prefix | ((unsigned)v << (byte * 8));
            sh_k = kk - cum;
        }
        __syncthreads();
    }
    if (tid == 0) { *outT = sh_prefix; *outNeedEq = sh_k; }
}

// ---------------- deterministic ordered compaction ----------------
__global__ __launch_bounds__(1024) void topk_compact(const float* __restrict__ raw,
                                                     const unsigned* pT, const int* pNeedEq,
                                                     int* keep, int* cid) {
    __shared__ int s_gt[1024], s_eq[1024];
    int tid = threadIdx.x;
    unsigned T = *pT;
    int needEq = *pNeedEq;
    int chunk = (N_NODES + 1023) / 1024;
    int lo = tid * chunk;
    int hi = lo + chunk; if (hi > N_NODES) hi = N_NODES;
    int cgt = 0, ceq = 0;
    for (int i = lo; i < hi; ++i) {
        unsigned k = fkey(raw[i]);
        if (k > T) cgt++;
        else if (k == T) ceq++;
    }
    s_gt[tid] = cgt; s_eq[tid] = ceq;
    __syncthreads();
    for (int off = 1; off < 1024; off <<= 1) {
        int a = (tid >= off) ? s_gt[tid - off] : 0;
        int b = (tid >= off) ? s_eq[tid - off] : 0;
        __syncthreads();
        s_gt[tid] += a; s_eq[tid] += b;
        __syncthreads();
    }
    int totalGt = s_gt[1023];
    int g = s_gt[tid] - cgt;
    int e = s_eq[tid] - ceq;
    for (int i = lo; i < hi; ++i) {
        unsigned k = fkey(raw[i]);
        if (k > T) { keep[i] = 1; cid[i] = g; g++; }
        else if (k == T) {
            if (e < needEq) { keep[i] = 1; cid[i] = totalGt + e; }
            else { keep[i] = 0; cid[i] = -1; }
            e++;
        } else { keep[i] = 0; cid[i] = -1; }
    }
}

// ---------------- global fallback cluster ----------------
__global__ __launch_bounds__(256) void bg_pack(const int* __restrict__ keep,
                                               const int* __restrict__ degS,
                                               const float* __restrict__ raw,
                                               unsigned long long* bestpack) {
    int i = blockIdx.x * blockDim.x + threadIdx.x;
    if (i < N_NODES && keep[i]) {
        unsigned long long p = ((unsigned long long)(unsigned)degS[i] << 32) | fkey(raw[i]);
        atomicMax(bestpack, p);
    }
}

__global__ __launch_bounds__(256) void bg_node(const int* __restrict__ keep,
                                               const int* __restrict__ degS,
                                               const float* __restrict__ raw,
                                               const unsigned long long* bestpack, int* bgnode) {
    int i = blockIdx.x * blockDim.x + threadIdx.x;
    if (i < N_NODES && keep[i]) {
        unsigned long long p = ((unsigned long long)(unsigned)degS[i] << 32) | fkey(raw[i]);
        if (p == *bestpack) atomicMin(bgnode, i);
    }
}

// ---------------- neighbor attachment ----------------
__global__ __launch_bounds__(256) void neigh_edges(const int* __restrict__ src,
                                                   const int* __restrict__ dst,
                                                   const int* __restrict__ keep,
                                                   const int* __restrict__ degS,
                                                   unsigned long long* best_enc) {
    int e = blockIdx.x * blockDim.x + threadIdx.x;
    if (e >= 2 * E_EDGES) return;
    int s, t;
    if (e < E_EDGES) { s = src[e]; t = dst[e]; }
    else { s = dst[e - E_EDGES]; t = src[e - E_EDGES]; }
    if (!keep[s] && keep[t]) {
        unsigned long long enc =
            (unsigned long long)((long long)degS[t] * N_NODES + (N_NODES - 1 - t)) + 1ULL;
        atomicMax(&best_enc[s], enc);
    }
}

__global__ __launch_bounds__(256) void resolve_cid(const int* __restrict__ keep,
                                                   const unsigned long long* __restrict__ best_enc,
                                                   const int* __restrict__ bgnode, int* cid) {
    int i = blockIdx.x * blockDim.x + threadIdx.x;
    if (i >= N_NODES) return;
    if (keep[i]) return;
    unsigned long long v = best_enc[i];
    if (v > 0ULL) {
        long long enc = (long long)(v - 1ULL);
        int t = (N_NODES - 1) - (int)(enc % N_NODES);
        cid[i] = cid[t];
    } else {
        cid[i] = cid[*bgnode];
    }
}

// ---------------- pooling ----------------
__global__ __launch_bounds__(256) void pool_add(const float* __restrict__ x1,
                                                const float* __restrict__ raw,
                                                const int* __restrict__ cid,
                                                float* xp, float* cnt) {
    int i = blockIdx.x, j = threadIdx.x;
    int c = cid[i];
    float g = tanhf(raw[i]);
    atomicAdd(&xp[(long)c * H_F + j], x1[(long)i * H_F + j] * g);
    if (j == 0) atomicAdd(&cnt[c], 1.0f);
}

__global__ __launch_bounds__(256) void pool_div(float* xp, const float* __restrict__ cnt) {
    int i = blockIdx.x, j = threadIdx.x;
    float c = fmaxf(cnt[i], 1.0f);
    xp[(long)i * H_F + j] /= c;
}

// ---------------- bit-packed pooled adjacency ----------------
__global__ __launch_bounds__(256) void build_Abits(const int* __restrict__ src,
                                                   const int* __restrict__ dst,
                                                   const int* __restrict__ cid,
                                                   unsigned* Abits) {
    int e = blockIdx.x * blockDim.x + threadIdx.x;
    if (e >= E_EDGES) return;
    int cu = cid[src[e]], cv = cid[dst[e]];
    if (cu != cv) atomicOr(&Abits[(long)cv * KW + (cu >> 5)], 1u << (cu & 31));
}

__global__ __launch_bounds__(256) void pop_di(const unsigned* __restrict__ Abits, float* di) {
    int i = blockIdx.x * blockDim.x + threadIdx.x;
    if (i >= K_CL) return;
    int c = 0;
    for (int w = 0; w < KW; ++w) c += __popc(Abits[(long)i * KW + w]);
    di[i] = rsqrtf((float)c + 1.0f);
}

__global__ __launch_bounds__(256) void scale_rows(const float* __restrict__ xpW2,
                                                  const float* __restrict__ di, float* Yp) {
    int i = blockIdx.x, j = threadIdx.x;
    Yp[(long)i * H_F + j] = di[i] * xpW2[(long)i * H_F + j];
}

// xp2[cv] = di[cv] * (sum_{A[cv][cu]=1} Yp[cu] + Yp[cv]) + b2
__global__ __launch_bounds__(256) void spmm_Z(const unsigned* __restrict__ Abits,
                                              const float* __restrict__ Yp,
                                              const float* __restrict__ di,
                                              const float* __restrict__ b2, float* xp2) {
    __shared__ unsigned s_row[KW];
    __shared__ float s_part[3][256];
    int cv = blockIdx.x;
    int tid = threadIdx.x;
    int w = tid >> 6, l = tid & 63;
    if (tid < KW) s_row[tid] = Abits[(long)cv * KW + tid];
    __syncthreads();
    float4 acc = {0.f, 0.f, 0.f, 0.f};
    const float4* Yp4 = (const float4*)Yp;
    for (int wi = w * (KW / 4); wi < (w + 1) * (KW / 4); ++wi) {
        unsigned word = s_row[wi];
        while (word) {
            int b = __ffs(word) - 1;
            word &= word - 1;
            int cu = wi * 32 + b;
            float4 y = Yp4[(long)cu * 64 + l];
            acc.x += y.x; acc.y += y.y; acc.z += y.z; acc.w += y.w;
        }
    }
    if (w > 0) *(float4*)&s_part[w - 1][l * 4] = acc;
    __syncthreads();
    if (w == 0) {
        #pragma unroll
        for (int ww = 0; ww < 3; ++ww) {
            float4 p = *(float4*)&s_part[ww][l * 4];
            acc.x += p.x; acc.y += p.y; acc.z += p.z; acc.w += p.w;
        }
        float dv = di[cv];
        float4 ys = Yp4[(long)cv * 64 + l];
        float4 o;
        o.x = dv * (acc.x + ys.x) + b2[l * 4 + 0];
        o.y = dv * (acc.y + ys.y) + b2[l * 4 + 1];
        o.z = dv * (acc.z + ys.z) + b2[l * 4 + 2];
        o.w = dv * (acc.w + ys.w) + b2[l * 4 + 3];
        *(float4*)&xp2[(long)cv * H_F + l * 4] = o;
    }
}

// ---------------- final add ----------------
__global__ __launch_bounds__(256) void final_add(float* out, const float* __restrict__ xp2,
                                                 const int* __restrict__ cid,
                                                 const float* __restrict__ b_skip) {
    int i = blockIdx.x, j = threadIdx.x;
    int c = cid[i];
    out[(long)i * OUT_F + j] += xp2[(long)c * OUT_F + j] + b_skip[j];
}

// ---------------- host launch ----------------
static inline size_t align256(size_t x) { return (x + 255) & ~(size_t)255; }

extern "C" void kernel_launch(void* const* d_in, const int* in_sizes, int n_in,
                              void* d_out, int out_size, void* d_ws, size_t ws_size,
                              hipStream_t stream) {
    const float* x      = (const float*)d_in[0];
    const int*   eidx   = (const int*)d_in[1];
    const float* W1     = (const float*)d_in[2];
    const float* b1     = (const float*)d_in[3];
    const float* W2     = (const float*)d_in[4];
    const float* b2     = (const float*)d_in[5];
    const float* wscore = (const float*)d_in[6];
    const float* Wskip  = (const float*)d_in[7];
    const float* bskip  = (const float*)d_in[8];
    float* out = (float*)d_out;

    const int* src = eidx;
    const int* dst = eidx + E_EDGES;

    char* ws = (char*)d_ws;
    size_t off = 0;
    auto alloc = [&](size_t bytes) { char* p = ws + off; off += align256(bytes); return p; };

    float* h     = (float*)alloc((size_t)N_NODES * H_F * 4);
    float* x1    = (float*)alloc((size_t)N_NODES * H_F * 4);
    float* raw   = (float*)alloc((size_t)N_NODES * 4);
    float* dinv  = (float*)alloc((size_t)N_NODES * 4);
    int*   cntD  = (int*)alloc((size_t)N_NODES * 4);
    int*   degS  = (int*)alloc((size_t)N_NODES * 4);
    int*   keep  = (int*)alloc((size_t)N_NODES * 4);
    int*   cid   = (int*)alloc((size_t)N_NODES * 4);
    unsigned long long* best_enc = (unsigned long long*)alloc((size_t)N_NODES * 8);
    int*   rowptr= (int*)alloc((size_t)(N_NODES + 1) * 4);
    int*   cur   = (int*)alloc((size_t)N_NODES * 4);
    int*   csr   = (int*)alloc((size_t)E_EDGES * 4);
    char*  small = alloc(64);
    unsigned* selT = (unsigned*)(small + 0);
    int* needEq    = (int*)(small + 4);
    unsigned long long* bestpack = (unsigned long long*)(small + 8);
    int* bgnode    = (int*)(small + 16);
    float* xp    = (float*)alloc((size_t)K_CL * H_F * 4);
    float* cnt   = (float*)alloc((size_t)K_CL * 4);
    unsigned* Abits = (unsigned*)alloc((size_t)K_CL * KW * 4);
    float* di    = (float*)alloc((size_t)K_CL * 4);
    float* xpW2  = (float*)alloc((size_t)K_CL * H_F * 4);
    float* Yp    = (float*)alloc((size_t)K_CL * H_F * 4);
    float* xp2   = (float*)alloc((size_t)K_CL * H_F * 4);
    (void)ws_size; (void)n_in; (void)in_sizes; (void)out_size;

    int nb = (N_NODES + 255) / 256;
    int eb = (E_EDGES + 255) / 256;

    // degrees
    init_nodes<<<nb, 256, 0, stream>>>(cntD, degS, best_enc, bestpack, bgnode);
    deg_edges<<<eb, 256, 0, stream>>>(src, dst, cntD, degS);
    make_dinv<<<nb, 256, 0, stream>>>(cntD, dinv);

    // h = x @ W1
    {
        dim3 grid(H_F / GBN, (N_NODES + GBM - 1) / GBM);
        gemm_fast<<<grid, 256, 0, stream>>>(x, W1, h, N_NODES, H_F, IN_F);
    }

    // CSR by dst + fused aggregation
    scan_rowptr<<<1, 1024, 0, stream>>>(cntD, rowptr, cur);
    csr_scatter<<<eb, 256, 0, stream>>>(src, dst, cur, csr);
    agg_fused<<<N_NODES, 256, 0, stream>>>(h, dinv, rowptr, csr, b1, wscore, x1, raw);

    // top-K
    topk_select<<<1, 1024, 0, stream>>>(raw, selT, needEq);
    topk_compact<<<1, 1024, 0, stream>>>(raw, selT, needEq, keep, cid);

    // fallback cluster
    bg_pack<<<nb, 256, 0, stream>>>(keep, degS, raw, bestpack);
    bg_node<<<nb, 256, 0, stream>>>(keep, degS, raw, bestpack, bgnode);

    // neighbor attachment
    neigh_edges<<<(2 * E_EDGES + 255) / 256, 256, 0, stream>>>(src, dst, keep, degS, best_enc);
    resolve_cid<<<nb, 256, 0, stream>>>(keep, best_enc, bgnode, cid);

    // pooling
    hipMemsetAsync(xp, 0, (size_t)K_CL * H_F * 4, stream);
    hipMemsetAsync(cnt, 0, (size_t)K_CL * 4, stream);
    pool_add<<<N_NODES, 256, 0, stream>>>(x1, raw, cid, xp, cnt);
    pool_div<<<K_CL, 256, 0, stream>>>(xp, cnt);

    // xpW2 = xp @ W2
    {
        dim3 grid(H_F / GBN, K_CL / GBM);
        gemm_fast<<<grid, 256, 0, stream>>>(xp, W2, xpW2, K_CL, H_F, H_F);
    }

    // bit-packed pooled adjacency
    hipMemsetAsync(Abits, 0, (size_t)K_CL * KW * 4, stream);
    build_Abits<<<eb, 256, 0, stream>>>(src, dst, cid, Abits);
    pop_di<<<(K_CL + 255) / 256, 256, 0, stream>>>(Abits, di);
    scale_rows<<<K_CL, 256, 0, stream>>>(xpW2, di, Yp);
    spmm_Z<<<K_CL, 256, 0, stream>>>(Abits, Yp, di, b2, xp2);

    // skip connection GEMM straight into out
    {
        dim3 grid(OUT_F / GBN, (N_NODES + GBM - 1) / GBM);
        gemm_fast<<<grid, 256, 0, stream>>>(x1, Wskip, out, N_NODES, OUT_F, H_F);
    }
    final_add<<<N_NODES, 256, 0, stream>>>(out, xp2, cid, bskip);
}